// Round 4
// baseline (370.407 us; speedup 1.0000x reference)
//
#include <hip/hip_runtime.h>
#include <math.h>

static constexpr float kSceneScale = 4.0f;
static constexpr int   kG     = 16;                 // sort grid per axis
static constexpr int   kNBins = kG * kG * kG + 1;   // 4097, +1 = "outside"
static constexpr int   kNB    = 256;                // histogram blocks
static constexpr int   kRes4  = 256;                // finest LOD
static constexpr int   kCells4 = kRes4 * kRes4 * kRes4;

__device__ __forceinline__ void fma4(float4& acc, float w, const float4& c) {
    acc.x = fmaf(w, c.x, acc.x);
    acc.y = fmaf(w, c.y, acc.y);
    acc.z = fmaf(w, c.z, acc.z);
    acc.w = fmaf(w, c.w, acc.w);
}

template <int RES>
__device__ __forceinline__ void trilerp_acc(const float4* __restrict__ cb,
                                            float x, float y, float z,
                                            float4& acc) {
    const float s = (float)(RES - 1);
    float fx = x * s, fy = y * s, fz = z * s;
    int x0 = min((int)fx, RES - 2);
    int y0 = min((int)fy, RES - 2);
    int z0 = min((int)fz, RES - 2);
    float tx = fx - (float)x0;
    float ty = fy - (float)y0;
    float tz = fz - (float)z0;

    int base = (x0 * RES + y0) * RES + z0;

    float4 c000 = cb[base];
    float4 c001 = cb[base + 1];
    float4 c010 = cb[base + RES];
    float4 c011 = cb[base + RES + 1];
    float4 c100 = cb[base + RES * RES];
    float4 c101 = cb[base + RES * RES + 1];
    float4 c110 = cb[base + RES * RES + RES];
    float4 c111 = cb[base + RES * RES + RES + 1];

    float wx0 = 1.0f - tx, wx1 = tx;
    float wy0 = 1.0f - ty, wy1 = ty;
    float wz0 = 1.0f - tz, wz1 = tz;

    fma4(acc, wx0 * wy0 * wz0, c000);
    fma4(acc, wx0 * wy0 * wz1, c001);
    fma4(acc, wx0 * wy1 * wz0, c010);
    fma4(acc, wx0 * wy1 * wz1, c011);
    fma4(acc, wx1 * wy0 * wz0, c100);
    fma4(acc, wx1 * wy0 * wz1, c101);
    fma4(acc, wx1 * wy1 * wz0, c110);
    fma4(acc, wx1 * wy1 * wz1, c111);
}

// decode 2 packed-bf16 words (one cell's 4 descriptors) into float4
__device__ __forceinline__ float4 bfdec(uint2 w) {
    float4 r;
    r.x = __uint_as_float(w.x << 16);
    r.y = __uint_as_float(w.x & 0xFFFF0000u);
    r.z = __uint_as_float(w.y << 16);
    r.w = __uint_as_float(w.y & 0xFFFF0000u);
    return r;
}

template <int RES>
__device__ __forceinline__ void trilerp_bf16(const uint2* __restrict__ cb,
                                             float x, float y, float z,
                                             float4& acc) {
    const float s = (float)(RES - 1);
    float fx = x * s, fy = y * s, fz = z * s;
    int x0 = min((int)fx, RES - 2);
    int y0 = min((int)fy, RES - 2);
    int z0 = min((int)fz, RES - 2);
    float tx = fx - (float)x0;
    float ty = fy - (float)y0;
    float tz = fz - (float)z0;

    int base = (x0 * RES + y0) * RES + z0;

    uint2 w000 = cb[base];
    uint2 w001 = cb[base + 1];
    uint2 w010 = cb[base + RES];
    uint2 w011 = cb[base + RES + 1];
    uint2 w100 = cb[base + RES * RES];
    uint2 w101 = cb[base + RES * RES + 1];
    uint2 w110 = cb[base + RES * RES + RES];
    uint2 w111 = cb[base + RES * RES + RES + 1];

    float wx0 = 1.0f - tx, wx1 = tx;
    float wy0 = 1.0f - ty, wy1 = ty;
    float wz0 = 1.0f - tz, wz1 = tz;

    fma4(acc, wx0 * wy0 * wz0, bfdec(w000));
    fma4(acc, wx0 * wy0 * wz1, bfdec(w001));
    fma4(acc, wx0 * wy1 * wz0, bfdec(w010));
    fma4(acc, wx0 * wy1 * wz1, bfdec(w011));
    fma4(acc, wx1 * wy0 * wz0, bfdec(w100));
    fma4(acc, wx1 * wy0 * wz1, bfdec(w101));
    fma4(acc, wx1 * wy1 * wz0, bfdec(w110));
    fma4(acc, wx1 * wy1 * wz1, bfdec(w111));
}

__device__ __forceinline__ void load_p01(const float* __restrict__ pts, int i,
                                         float& x, float& y, float& z, bool& inside) {
    float px = pts[3 * i + 0] * (1.0f / kSceneScale);
    float py = pts[3 * i + 1] * (1.0f / kSceneScale);
    float pz = pts[3 * i + 2] * (1.0f / kSceneScale);
    inside = (fabsf(px) < 0.5f) && (fabsf(py) < 0.5f) && (fabsf(pz) < 0.5f);
    x = fminf(fmaxf(px + 0.5f, 0.0f), 1.0f);
    y = fminf(fmaxf(py + 0.5f, 0.0f), 1.0f);
    z = fminf(fmaxf(pz + 0.5f, 0.0f), 1.0f);
}

__device__ __forceinline__ unsigned point_key(const float* __restrict__ pts, int i) {
    float x, y, z; bool inside;
    load_p01(pts, i, x, y, z, inside);
    if (!inside) return (unsigned)(kNBins - 1);
    int bx = min((int)(x * kG), kG - 1);
    int by = min((int)(y * kG), kG - 1);
    int bz = min((int)(z * kG), kG - 1);
    return (unsigned)((bx * kG + by) * kG + bz);
}

// ---------- Pass A: per-block LDS histogram ----------
__global__ __launch_bounds__(256) void keys_hist_kernel(
        const float* __restrict__ pts, unsigned* __restrict__ keys,
        unsigned* __restrict__ blockHist, int n, int chunk) {
    __shared__ unsigned hist[kNBins];
    int tid = threadIdx.x;
    for (int j = tid; j < kNBins; j += 256) hist[j] = 0;
    __syncthreads();
    int beg = blockIdx.x * chunk;
    int end = min(n, beg + chunk);
    for (int i = beg + tid; i < end; i += 256) {
        unsigned key = point_key(pts, i);
        keys[i] = key;
        atomicAdd(&hist[key], 1u);
    }
    __syncthreads();
    for (int j = tid; j < kNBins; j += 256) blockHist[(size_t)j * kNB + blockIdx.x] = hist[j];
}

// ---------- Pass B1: scan 1024-element chunks ----------
__global__ __launch_bounds__(256) void scan_chunks_kernel(
        unsigned* __restrict__ data, unsigned* __restrict__ partials, int total) {
    __shared__ unsigned sums[256];
    int tid = threadIdx.x;
    int base = blockIdx.x * 1024 + tid * 4;
    uint4 v = make_uint4(0u, 0u, 0u, 0u);
    if (base + 3 < total) {
        v = *(const uint4*)(data + base);
    } else {
        unsigned* p = (unsigned*)&v;
        for (int k = 0; k < 4; ++k) if (base + k < total) p[k] = data[base + k];
    }
    unsigned s1 = v.x + v.y, s2 = s1 + v.z, s3 = s2 + v.w;
    sums[tid] = s3;
    __syncthreads();
    for (int off = 1; off < 256; off <<= 1) {
        unsigned t = (tid >= off) ? sums[tid - off] : 0u;
        __syncthreads();
        sums[tid] += t;
        __syncthreads();
    }
    unsigned excl = sums[tid] - s3;
    uint4 o;
    o.x = excl; o.y = excl + v.x; o.z = excl + s1; o.w = excl + s2;
    if (base + 3 < total) {
        *(uint4*)(data + base) = o;
    } else {
        unsigned* p = (unsigned*)&o;
        for (int k = 0; k < 4; ++k) if (base + k < total) data[base + k] = p[k];
    }
    if (tid == 255) partials[blockIdx.x] = sums[255];
}

// ---------- Pass B2: scan partials (1 block) ----------
__global__ __launch_bounds__(256) void scan_partials_kernel(unsigned* __restrict__ partials, int m) {
    __shared__ unsigned buf[256];
    __shared__ unsigned carry_s;
    int tid = threadIdx.x;
    if (tid == 0) carry_s = 0u;
    __syncthreads();
    for (int base = 0; base < m; base += 256) {
        unsigned v = (base + tid < m) ? partials[base + tid] : 0u;
        buf[tid] = v;
        __syncthreads();
        for (int off = 1; off < 256; off <<= 1) {
            unsigned t = (tid >= off) ? buf[tid - off] : 0u;
            __syncthreads();
            buf[tid] += t;
            __syncthreads();
        }
        unsigned incl = buf[tid];
        unsigned c = carry_s;
        if (base + tid < m) partials[base + tid] = c + incl - v;
        __syncthreads();
        if (tid == 255) carry_s = c + incl;
        __syncthreads();
    }
}

// ---------- Pass B3: add chunk offsets back ----------
__global__ __launch_bounds__(256) void scan_add_kernel(
        unsigned* __restrict__ data, const unsigned* __restrict__ partials, int total) {
    int tid = threadIdx.x;
    int base = blockIdx.x * 1024 + tid * 4;
    unsigned p = partials[blockIdx.x];
    if (base + 3 < total) {
        uint4 v = *(const uint4*)(data + base);
        v.x += p; v.y += p; v.z += p; v.w += p;
        *(uint4*)(data + base) = v;
    } else {
        for (int k = 0; k < 4; ++k) if (base + k < total) data[base + k] += p;
    }
}

// ---------- Pass C: scatter sorted point payloads (LDS atomics) ----------
__global__ __launch_bounds__(256) void scatter_kernel(
        const float* __restrict__ pts,
        const unsigned* __restrict__ keys, const unsigned* __restrict__ blockHist,
        float4* __restrict__ spts, int n, int chunk) {
    __shared__ unsigned offs[kNBins];
    int tid = threadIdx.x;
    for (int j = tid; j < kNBins; j += 256) offs[j] = blockHist[(size_t)j * kNB + blockIdx.x];
    __syncthreads();
    int beg = blockIdx.x * chunk;
    int end = min(n, beg + chunk);
    for (int i = beg + tid; i < end; i += 256) {
        unsigned k = keys[i];
        float x, y, z; bool inside;
        load_p01(pts, i, x, y, z, inside);
        unsigned pos = atomicAdd(&offs[k], 1u);
        unsigned tag = (unsigned)i | (inside ? 0x80000000u : 0u);
        spts[pos] = make_float4(x, y, z, __uint_as_float(tag));
    }
}

// ---------- Pass Conv: cb4 fp32 -> packed bf16 ----------
__device__ __forceinline__ unsigned bf16r(float f) {
    unsigned u = __float_as_uint(f);
    return (u + 0x7FFFu + ((u >> 16) & 1u)) >> 16;   // RTNE; inputs are finite
}
__device__ __forceinline__ unsigned pk2(float lo, float hi) {
    return bf16r(lo) | (bf16r(hi) << 16);
}
__global__ __launch_bounds__(256) void convert_cb4_kernel(
        const float4* __restrict__ src, uint4* __restrict__ dst, int npairs) {
    int t = blockIdx.x * blockDim.x + threadIdx.x;
    if (t >= npairs) return;
    float4 a = src[2 * t];
    float4 b = src[2 * t + 1];
    dst[t] = make_uint4(pk2(a.x, a.y), pk2(a.z, a.w), pk2(b.x, b.y), pk2(b.z, b.w));
}

// ---------- bijective XCD-contiguous swizzle (m204 form) ----------
__device__ __forceinline__ int xcd_swz(int orig, int nwg) {
    const int NX = 8;
    int q = nwg / NX, r = nwg % NX;
    int xcd = orig % NX, j = orig / NX;
    int base = (xcd < r) ? xcd * (q + 1) : r * (q + 1) + (xcd - r) * q;
    return base + j;
}

// ---------- Pass D: sorted streaming compute, bf16 cb4 ----------
__global__ __launch_bounds__(256) void compute_bf16_kernel(
        const float4* __restrict__ spts,
        const float4* __restrict__ cb0,
        const float4* __restrict__ cb1,
        const float4* __restrict__ cb2,
        const float4* __restrict__ cb3,
        const uint2*  __restrict__ cb4b,
        float* __restrict__ out,
        int n, int nwg) {
    int bid = xcd_swz(blockIdx.x, nwg);
    int t = bid * blockDim.x + threadIdx.x;
    if (t >= n) return;
    float4 s = spts[t];
    unsigned tag = __float_as_uint(s.w);
    bool inside = (tag & 0x80000000u) != 0u;
    int i = (int)(tag & 0x7FFFFFFFu);

    float c0 = 0.0f, c1 = 0.0f, c2 = 0.0f, sg = 0.0f;
    if (inside) {
        float4 acc = make_float4(0.0f, 0.0f, 0.0f, 0.0f);
        trilerp_acc<16>(cb0, s.x, s.y, s.z, acc);
        trilerp_acc<32>(cb1, s.x, s.y, s.z, acc);
        trilerp_acc<64>(cb2, s.x, s.y, s.z, acc);
        trilerp_acc<128>(cb3, s.x, s.y, s.z, acc);
        trilerp_bf16<256>(cb4b, s.x, s.y, s.z, acc);
        c0 = acc.x; c1 = acc.y; c2 = acc.z; sg = expf(acc.w);
    }
    out[3 * i + 0] = c0;
    out[3 * i + 1] = c1;
    out[3 * i + 2] = c2;
    out[(size_t)3 * n + i] = sg;
}

// ---------- Tier-2: sorted streaming compute, fp32 cb4 ----------
__global__ __launch_bounds__(256) void compute_fp32_kernel(
        const float4* __restrict__ spts,
        const float4* __restrict__ cb0,
        const float4* __restrict__ cb1,
        const float4* __restrict__ cb2,
        const float4* __restrict__ cb3,
        const float4* __restrict__ cb4,
        float* __restrict__ out,
        int n, int nwg) {
    int bid = xcd_swz(blockIdx.x, nwg);
    int t = bid * blockDim.x + threadIdx.x;
    if (t >= n) return;
    float4 s = spts[t];
    unsigned tag = __float_as_uint(s.w);
    bool inside = (tag & 0x80000000u) != 0u;
    int i = (int)(tag & 0x7FFFFFFFu);

    float c0 = 0.0f, c1 = 0.0f, c2 = 0.0f, sg = 0.0f;
    if (inside) {
        float4 acc = make_float4(0.0f, 0.0f, 0.0f, 0.0f);
        trilerp_acc<16>(cb0, s.x, s.y, s.z, acc);
        trilerp_acc<32>(cb1, s.x, s.y, s.z, acc);
        trilerp_acc<64>(cb2, s.x, s.y, s.z, acc);
        trilerp_acc<128>(cb3, s.x, s.y, s.z, acc);
        trilerp_acc<256>(cb4, s.x, s.y, s.z, acc);
        c0 = acc.x; c1 = acc.y; c2 = acc.z; sg = expf(acc.w);
    }
    out[3 * i + 0] = c0;
    out[3 * i + 1] = c1;
    out[3 * i + 2] = c2;
    out[(size_t)3 * n + i] = sg;
}

// ---------- Tier-3: direct kernel ----------
__global__ __launch_bounds__(256) void direct_kernel(
        const float* __restrict__ pts,
        const float4* __restrict__ cb0,
        const float4* __restrict__ cb1,
        const float4* __restrict__ cb2,
        const float4* __restrict__ cb3,
        const float4* __restrict__ cb4,
        float* __restrict__ out,
        int n) {
    int i = blockIdx.x * blockDim.x + threadIdx.x;
    if (i >= n) return;
    float x, y, z; bool inside;
    load_p01(pts, i, x, y, z, inside);
    float c0 = 0.0f, c1 = 0.0f, c2 = 0.0f, sg = 0.0f;
    if (inside) {
        float4 acc = make_float4(0.0f, 0.0f, 0.0f, 0.0f);
        trilerp_acc<16>(cb0, x, y, z, acc);
        trilerp_acc<32>(cb1, x, y, z, acc);
        trilerp_acc<64>(cb2, x, y, z, acc);
        trilerp_acc<128>(cb3, x, y, z, acc);
        trilerp_acc<256>(cb4, x, y, z, acc);
        c0 = acc.x; c1 = acc.y; c2 = acc.z; sg = expf(acc.w);
    }
    out[3 * i + 0] = c0;
    out[3 * i + 1] = c1;
    out[3 * i + 2] = c2;
    out[(size_t)3 * n + i] = sg;
}

extern "C" void kernel_launch(void* const* d_in, const int* in_sizes, int n_in,
                              void* d_out, int out_size, void* d_ws, size_t ws_size,
                              hipStream_t stream) {
    const float* pts = (const float*)d_in[0];
    const float4* cb0 = (const float4*)d_in[2];
    const float4* cb1 = (const float4*)d_in[3];
    const float4* cb2 = (const float4*)d_in[4];
    const float4* cb3 = (const float4*)d_in[5];
    const float4* cb4 = (const float4*)d_in[6];
    float* out = (float*)d_out;

    int n = in_sizes[0] / 3;

    const int histTotal = kNBins * kNB;
    const int nChunks   = (histTotal + 1023) / 1024;

    size_t off_keys = 0;
    size_t off_spts = (off_keys + (size_t)n * 4 + 15) & ~(size_t)15;
    size_t off_hist = off_spts + (size_t)n * 16;
    size_t off_part = off_hist + (size_t)histTotal * 4;
    size_t off_cb4b = (off_part + (size_t)nChunks * 4 + 255) & ~(size_t)255;
    size_t need_sort = off_part + (size_t)nChunks * 4;
    size_t need_bf16 = off_cb4b + (size_t)kCells4 * 8;

    dim3 block(256);
    int nwg = (n + 255) / 256;

    if (ws_size < need_sort) {
        direct_kernel<<<dim3(nwg), block, 0, stream>>>(pts, cb0, cb1, cb2, cb3, cb4, out, n);
        return;
    }

    unsigned* keys      = (unsigned*)((char*)d_ws + off_keys);
    float4*   spts      = (float4*)((char*)d_ws + off_spts);
    unsigned* blockHist = (unsigned*)((char*)d_ws + off_hist);
    unsigned* partials  = (unsigned*)((char*)d_ws + off_part);
    uint2*    cb4b      = (uint2*)((char*)d_ws + off_cb4b);

    int chunk = (n + kNB - 1) / kNB;

    keys_hist_kernel<<<dim3(kNB), block, 0, stream>>>(pts, keys, blockHist, n, chunk);
    scan_chunks_kernel<<<dim3(nChunks), block, 0, stream>>>(blockHist, partials, histTotal);
    scan_partials_kernel<<<dim3(1), block, 0, stream>>>(partials, nChunks);
    scan_add_kernel<<<dim3(nChunks), block, 0, stream>>>(blockHist, partials, histTotal);
    scatter_kernel<<<dim3(kNB), block, 0, stream>>>(pts, keys, blockHist, spts, n, chunk);

    if (ws_size >= need_bf16) {
        const int npairs = kCells4 / 2;
        convert_cb4_kernel<<<dim3(npairs / 256), block, 0, stream>>>(cb4, (uint4*)cb4b, npairs);
        compute_bf16_kernel<<<dim3(nwg), block, 0, stream>>>(
            spts, cb0, cb1, cb2, cb3, (const uint2*)cb4b, out, n, nwg);
    } else {
        compute_fp32_kernel<<<dim3(nwg), block, 0, stream>>>(
            spts, cb0, cb1, cb2, cb3, cb4, out, n, nwg);
    }
}

// Round 5
// 320.677 us; speedup vs baseline: 1.1551x; 1.1551x over previous
//
#include <hip/hip_runtime.h>
#include <math.h>

static constexpr float kSceneScale = 4.0f;
static constexpr int   kG     = 16;                 // sort grid per axis
static constexpr int   kNBins = kG * kG * kG + 1;   // 4097, +1 = "outside"
static constexpr int   kNB    = 256;                // histogram blocks
static constexpr int   kDirectThresh = 48;          // bins below this skip LDS staging

// staged spans per LOD (max cells touched by one bin, incl. +1 corner, see derivation)
static constexpr int kS4 = 18;   // res 256
static constexpr int kS3 = 10;   // res 128
static constexpr int kS2 = 6;    // res 64
static constexpr int kS1 = 4;    // res 32
static constexpr int kS0 = 3;    // res 16

__device__ __forceinline__ void fma4(float4& acc, float w, const float4& c) {
    acc.x = fmaf(w, c.x, acc.x);
    acc.y = fmaf(w, c.y, acc.y);
    acc.z = fmaf(w, c.z, acc.z);
    acc.w = fmaf(w, c.w, acc.w);
}

__device__ __forceinline__ unsigned bf16r(float f) {
    unsigned u = __float_as_uint(f);
    return (u + 0x7FFFu + ((u >> 16) & 1u)) >> 16;   // RTNE; inputs finite
}
__device__ __forceinline__ unsigned pk2(float lo, float hi) {
    return bf16r(lo) | (bf16r(hi) << 16);
}
__device__ __forceinline__ float4 bfdec(uint2 w) {
    float4 r;
    r.x = __uint_as_float(w.x << 16);
    r.y = __uint_as_float(w.x & 0xFFFF0000u);
    r.z = __uint_as_float(w.y << 16);
    r.w = __uint_as_float(w.y & 0xFFFF0000u);
    return r;
}

template <int RES>
__device__ __forceinline__ void trilerp_acc(const float4* __restrict__ cb,
                                            float x, float y, float z,
                                            float4& acc) {
    const float s = (float)(RES - 1);
    float fx = x * s, fy = y * s, fz = z * s;
    int x0 = min((int)fx, RES - 2);
    int y0 = min((int)fy, RES - 2);
    int z0 = min((int)fz, RES - 2);
    float tx = fx - (float)x0;
    float ty = fy - (float)y0;
    float tz = fz - (float)z0;
    int base = (x0 * RES + y0) * RES + z0;
    float4 c000 = cb[base];
    float4 c001 = cb[base + 1];
    float4 c010 = cb[base + RES];
    float4 c011 = cb[base + RES + 1];
    float4 c100 = cb[base + RES * RES];
    float4 c101 = cb[base + RES * RES + 1];
    float4 c110 = cb[base + RES * RES + RES];
    float4 c111 = cb[base + RES * RES + RES + 1];
    float wx0 = 1.0f - tx, wx1 = tx;
    float wy0 = 1.0f - ty, wy1 = ty;
    float wz0 = 1.0f - tz, wz1 = tz;
    fma4(acc, wx0 * wy0 * wz0, c000);
    fma4(acc, wx0 * wy0 * wz1, c001);
    fma4(acc, wx0 * wy1 * wz0, c010);
    fma4(acc, wx0 * wy1 * wz1, c011);
    fma4(acc, wx1 * wy0 * wz0, c100);
    fma4(acc, wx1 * wy0 * wz1, c101);
    fma4(acc, wx1 * wy1 * wz0, c110);
    fma4(acc, wx1 * wy1 * wz1, c111);
}

__device__ __forceinline__ void load_p01(const float* __restrict__ pts, int i,
                                         float& x, float& y, float& z, bool& inside) {
    float px = pts[3 * i + 0] * (1.0f / kSceneScale);
    float py = pts[3 * i + 1] * (1.0f / kSceneScale);
    float pz = pts[3 * i + 2] * (1.0f / kSceneScale);
    inside = (fabsf(px) < 0.5f) && (fabsf(py) < 0.5f) && (fabsf(pz) < 0.5f);
    x = fminf(fmaxf(px + 0.5f, 0.0f), 1.0f);
    y = fminf(fmaxf(py + 0.5f, 0.0f), 1.0f);
    z = fminf(fmaxf(pz + 0.5f, 0.0f), 1.0f);
}

__device__ __forceinline__ unsigned point_key(const float* __restrict__ pts, int i) {
    float x, y, z; bool inside;
    load_p01(pts, i, x, y, z, inside);
    if (!inside) return (unsigned)(kNBins - 1);
    int bx = min((int)(x * kG), kG - 1);
    int by = min((int)(y * kG), kG - 1);
    int bz = min((int)(z * kG), kG - 1);
    return (unsigned)((bx * kG + by) * kG + bz);
}

// ---------- Pass A: per-block LDS histogram ----------
__global__ __launch_bounds__(256) void keys_hist_kernel(
        const float* __restrict__ pts, unsigned* __restrict__ keys,
        unsigned* __restrict__ blockHist, int n, int chunk) {
    __shared__ unsigned hist[kNBins];
    int tid = threadIdx.x;
    for (int j = tid; j < kNBins; j += 256) hist[j] = 0;
    __syncthreads();
    int beg = blockIdx.x * chunk;
    int end = min(n, beg + chunk);
    for (int i = beg + tid; i < end; i += 256) {
        unsigned key = point_key(pts, i);
        keys[i] = key;
        atomicAdd(&hist[key], 1u);
    }
    __syncthreads();
    for (int j = tid; j < kNBins; j += 256) blockHist[(size_t)j * kNB + blockIdx.x] = hist[j];
}

// ---------- Pass B1: scan 1024-element chunks ----------
__global__ __launch_bounds__(256) void scan_chunks_kernel(
        unsigned* __restrict__ data, unsigned* __restrict__ partials, int total) {
    __shared__ unsigned sums[256];
    int tid = threadIdx.x;
    int base = blockIdx.x * 1024 + tid * 4;
    uint4 v = make_uint4(0u, 0u, 0u, 0u);
    if (base + 3 < total) {
        v = *(const uint4*)(data + base);
    } else {
        unsigned* p = (unsigned*)&v;
        for (int k = 0; k < 4; ++k) if (base + k < total) p[k] = data[base + k];
    }
    unsigned s1 = v.x + v.y, s2 = s1 + v.z, s3 = s2 + v.w;
    sums[tid] = s3;
    __syncthreads();
    for (int off = 1; off < 256; off <<= 1) {
        unsigned t = (tid >= off) ? sums[tid - off] : 0u;
        __syncthreads();
        sums[tid] += t;
        __syncthreads();
    }
    unsigned excl = sums[tid] - s3;
    uint4 o;
    o.x = excl; o.y = excl + v.x; o.z = excl + s1; o.w = excl + s2;
    if (base + 3 < total) {
        *(uint4*)(data + base) = o;
    } else {
        unsigned* p = (unsigned*)&o;
        for (int k = 0; k < 4; ++k) if (base + k < total) data[base + k] = p[k];
    }
    if (tid == 255) partials[blockIdx.x] = sums[255];
}

// ---------- Pass B2: scan partials (1 block) ----------
__global__ __launch_bounds__(256) void scan_partials_kernel(unsigned* __restrict__ partials, int m) {
    __shared__ unsigned buf[256];
    __shared__ unsigned carry_s;
    int tid = threadIdx.x;
    if (tid == 0) carry_s = 0u;
    __syncthreads();
    for (int base = 0; base < m; base += 256) {
        unsigned v = (base + tid < m) ? partials[base + tid] : 0u;
        buf[tid] = v;
        __syncthreads();
        for (int off = 1; off < 256; off <<= 1) {
            unsigned t = (tid >= off) ? buf[tid - off] : 0u;
            __syncthreads();
            buf[tid] += t;
            __syncthreads();
        }
        unsigned incl = buf[tid];
        unsigned c = carry_s;
        if (base + tid < m) partials[base + tid] = c + incl - v;
        __syncthreads();
        if (tid == 255) carry_s = c + incl;
        __syncthreads();
    }
}

// ---------- Pass B3: add chunk offsets back ----------
__global__ __launch_bounds__(256) void scan_add_kernel(
        unsigned* __restrict__ data, const unsigned* __restrict__ partials, int total) {
    int tid = threadIdx.x;
    int base = blockIdx.x * 1024 + tid * 4;
    unsigned p = partials[blockIdx.x];
    if (base + 3 < total) {
        uint4 v = *(const uint4*)(data + base);
        v.x += p; v.y += p; v.z += p; v.w += p;
        *(uint4*)(data + base) = v;
    } else {
        for (int k = 0; k < 4; ++k) if (base + k < total) data[base + k] += p;
    }
}

// ---------- Pass C: scatter payloads; outside points write zeros here ----------
__global__ __launch_bounds__(256) void scatter_kernel(
        const float* __restrict__ pts,
        const unsigned* __restrict__ keys, const unsigned* __restrict__ blockHist,
        float4* __restrict__ spts, float* __restrict__ out, int n, int chunk) {
    __shared__ unsigned offs[kNBins];
    int tid = threadIdx.x;
    for (int j = tid; j < kNBins; j += 256) offs[j] = blockHist[(size_t)j * kNB + blockIdx.x];
    __syncthreads();
    int beg = blockIdx.x * chunk;
    int end = min(n, beg + chunk);
    for (int i = beg + tid; i < end; i += 256) {
        unsigned k = keys[i];
        float x, y, z; bool inside;
        load_p01(pts, i, x, y, z, inside);
        unsigned pos = atomicAdd(&offs[k], 1u);
        if (inside) {
            spts[pos] = make_float4(x, y, z, __uint_as_float((unsigned)i));
        } else {
            out[3 * i + 0] = 0.0f;
            out[3 * i + 1] = 0.0f;
            out[3 * i + 2] = 0.0f;
            out[(size_t)3 * n + i] = 0.0f;
        }
    }
}

// ---------- staging helpers ----------
template <int RES, int SPAN>
__device__ __forceinline__ void stage_bf16(const float4* __restrict__ cb, uint2* sbuf,
                                           int lox, int loy, int loz, int tid, int nthr) {
    for (int c = tid; c < SPAN * SPAN * SPAN; c += nthr) {
        int cz = c % SPAN;
        int cy = (c / SPAN) % SPAN;
        int cx = c / (SPAN * SPAN);
        int gx = min(lox + cx, RES - 1);
        int gy = min(loy + cy, RES - 1);
        int gz = min(loz + cz, RES - 1);
        float4 v = cb[((size_t)gx * RES + gy) * RES + gz];
        sbuf[c] = make_uint2(pk2(v.x, v.y), pk2(v.z, v.w));
    }
}

template <int RES, int SPAN>
__device__ __forceinline__ void stage_f32(const float4* __restrict__ cb, float4* sbuf,
                                          int lox, int loy, int loz, int tid, int nthr) {
    for (int c = tid; c < SPAN * SPAN * SPAN; c += nthr) {
        int cz = c % SPAN;
        int cy = (c / SPAN) % SPAN;
        int cx = c / (SPAN * SPAN);
        int gx = min(lox + cx, RES - 1);
        int gy = min(loy + cy, RES - 1);
        int gz = min(loz + cz, RES - 1);
        sbuf[c] = cb[((size_t)gx * RES + gy) * RES + gz];
    }
}

// ---------- LDS trilerp ----------
template <int RES, int SPAN>
__device__ __forceinline__ void lerp_lds_bf16(const uint2* sbuf,
                                              int lox, int loy, int loz,
                                              float x, float y, float z, float4& acc) {
    const float s = (float)(RES - 1);
    float fx = x * s, fy = y * s, fz = z * s;
    int x0 = min((int)fx, RES - 2);
    int y0 = min((int)fy, RES - 2);
    int z0 = min((int)fz, RES - 2);
    float tx = fx - (float)x0;
    float ty = fy - (float)y0;
    float tz = fz - (float)z0;
    int base = ((x0 - lox) * SPAN + (y0 - loy)) * SPAN + (z0 - loz);
    uint2 w000 = sbuf[base];
    uint2 w001 = sbuf[base + 1];
    uint2 w010 = sbuf[base + SPAN];
    uint2 w011 = sbuf[base + SPAN + 1];
    uint2 w100 = sbuf[base + SPAN * SPAN];
    uint2 w101 = sbuf[base + SPAN * SPAN + 1];
    uint2 w110 = sbuf[base + SPAN * SPAN + SPAN];
    uint2 w111 = sbuf[base + SPAN * SPAN + SPAN + 1];
    float wx0 = 1.0f - tx, wx1 = tx;
    float wy0 = 1.0f - ty, wy1 = ty;
    float wz0 = 1.0f - tz, wz1 = tz;
    fma4(acc, wx0 * wy0 * wz0, bfdec(w000));
    fma4(acc, wx0 * wy0 * wz1, bfdec(w001));
    fma4(acc, wx0 * wy1 * wz0, bfdec(w010));
    fma4(acc, wx0 * wy1 * wz1, bfdec(w011));
    fma4(acc, wx1 * wy0 * wz0, bfdec(w100));
    fma4(acc, wx1 * wy0 * wz1, bfdec(w101));
    fma4(acc, wx1 * wy1 * wz0, bfdec(w110));
    fma4(acc, wx1 * wy1 * wz1, bfdec(w111));
}

template <int RES, int SPAN>
__device__ __forceinline__ void lerp_lds_f32(const float4* sbuf,
                                             int lox, int loy, int loz,
                                             float x, float y, float z, float4& acc) {
    const float s = (float)(RES - 1);
    float fx = x * s, fy = y * s, fz = z * s;
    int x0 = min((int)fx, RES - 2);
    int y0 = min((int)fy, RES - 2);
    int z0 = min((int)fz, RES - 2);
    float tx = fx - (float)x0;
    float ty = fy - (float)y0;
    float tz = fz - (float)z0;
    int base = ((x0 - lox) * SPAN + (y0 - loy)) * SPAN + (z0 - loz);
    float4 c000 = sbuf[base];
    float4 c001 = sbuf[base + 1];
    float4 c010 = sbuf[base + SPAN];
    float4 c011 = sbuf[base + SPAN + 1];
    float4 c100 = sbuf[base + SPAN * SPAN];
    float4 c101 = sbuf[base + SPAN * SPAN + 1];
    float4 c110 = sbuf[base + SPAN * SPAN + SPAN];
    float4 c111 = sbuf[base + SPAN * SPAN + SPAN + 1];
    float wx0 = 1.0f - tx, wx1 = tx;
    float wy0 = 1.0f - ty, wy1 = ty;
    float wz0 = 1.0f - tz, wz1 = tz;
    fma4(acc, wx0 * wy0 * wz0, c000);
    fma4(acc, wx0 * wy0 * wz1, c001);
    fma4(acc, wx0 * wy1 * wz0, c010);
    fma4(acc, wx0 * wy1 * wz1, c011);
    fma4(acc, wx1 * wy0 * wz0, c100);
    fma4(acc, wx1 * wy0 * wz1, c101);
    fma4(acc, wx1 * wy1 * wz0, c110);
    fma4(acc, wx1 * wy1 * wz1, c111);
}

// ---------- Pass D: one block per bin; stage bin sub-grids to LDS ----------
__global__ __launch_bounds__(512) void compute_tiled_kernel(
        const float4* __restrict__ spts,
        const unsigned* __restrict__ blockHist,
        const float4* __restrict__ cb0,
        const float4* __restrict__ cb1,
        const float4* __restrict__ cb2,
        const float4* __restrict__ cb3,
        const float4* __restrict__ cb4,
        float* __restrict__ out,
        int n) {
    int bin = blockIdx.x;                    // 0..4095 (outside bin excluded)
    unsigned start = blockHist[(size_t)bin * kNB];
    unsigned end   = blockHist[(size_t)(bin + 1) * kNB];
    if (start >= end) return;

    int bx = bin >> 8, by = (bin >> 4) & 15, bz = bin & 15;
    int tid = threadIdx.x;

    if ((int)(end - start) < kDirectThresh) {
        // sparse bin: direct global gathers, skip staging
        for (unsigned t = start + tid; t < end; t += 512) {
            float4 s = spts[t];
            int i = (int)__float_as_uint(s.w);
            float4 acc = make_float4(0.0f, 0.0f, 0.0f, 0.0f);
            trilerp_acc<16>(cb0, s.x, s.y, s.z, acc);
            trilerp_acc<32>(cb1, s.x, s.y, s.z, acc);
            trilerp_acc<64>(cb2, s.x, s.y, s.z, acc);
            trilerp_acc<128>(cb3, s.x, s.y, s.z, acc);
            trilerp_acc<256>(cb4, s.x, s.y, s.z, acc);
            out[3 * i + 0] = acc.x;
            out[3 * i + 1] = acc.y;
            out[3 * i + 2] = acc.z;
            out[(size_t)3 * n + i] = expf(acc.w);
        }
        return;
    }

    __shared__ uint2  s4[kS4 * kS4 * kS4];   // 46656 B  (bf16 cb4)
    __shared__ uint2  s3[kS3 * kS3 * kS3];   //  8000 B  (bf16 cb3)
    __shared__ float4 s2[kS2 * kS2 * kS2];   //  3456 B
    __shared__ float4 s1[kS1 * kS1 * kS1];   //  1024 B
    __shared__ float4 s0[kS0 * kS0 * kS0];   //   432 B

    int lox4 = (bx * 255) >> 4, loy4 = (by * 255) >> 4, loz4 = (bz * 255) >> 4;
    int lox3 = (bx * 127) >> 4, loy3 = (by * 127) >> 4, loz3 = (bz * 127) >> 4;
    int lox2 = (bx * 63) >> 4,  loy2 = (by * 63) >> 4,  loz2 = (bz * 63) >> 4;
    int lox1 = (bx * 31) >> 4,  loy1 = (by * 31) >> 4,  loz1 = (bz * 31) >> 4;
    int lox0 = (bx * 15) >> 4,  loy0 = (by * 15) >> 4,  loz0 = (bz * 15) >> 4;

    stage_bf16<256, kS4>(cb4, s4, lox4, loy4, loz4, tid, 512);
    stage_bf16<128, kS3>(cb3, s3, lox3, loy3, loz3, tid, 512);
    stage_f32<64,  kS2>(cb2, s2, lox2, loy2, loz2, tid, 512);
    stage_f32<32,  kS1>(cb1, s1, lox1, loy1, loz1, tid, 512);
    stage_f32<16,  kS0>(cb0, s0, lox0, loy0, loz0, tid, 512);
    __syncthreads();

    for (unsigned t = start + tid; t < end; t += 512) {
        float4 s = spts[t];
        int i = (int)__float_as_uint(s.w);
        float4 acc = make_float4(0.0f, 0.0f, 0.0f, 0.0f);
        lerp_lds_f32<16,  kS0>(s0, lox0, loy0, loz0, s.x, s.y, s.z, acc);
        lerp_lds_f32<32,  kS1>(s1, lox1, loy1, loz1, s.x, s.y, s.z, acc);
        lerp_lds_f32<64,  kS2>(s2, lox2, loy2, loz2, s.x, s.y, s.z, acc);
        lerp_lds_bf16<128, kS3>(s3, lox3, loy3, loz3, s.x, s.y, s.z, acc);
        lerp_lds_bf16<256, kS4>(s4, lox4, loy4, loz4, s.x, s.y, s.z, acc);
        out[3 * i + 0] = acc.x;
        out[3 * i + 1] = acc.y;
        out[3 * i + 2] = acc.z;
        out[(size_t)3 * n + i] = expf(acc.w);
    }
}

// ---------- Fallback: direct kernel ----------
__global__ __launch_bounds__(256) void direct_kernel(
        const float* __restrict__ pts,
        const float4* __restrict__ cb0,
        const float4* __restrict__ cb1,
        const float4* __restrict__ cb2,
        const float4* __restrict__ cb3,
        const float4* __restrict__ cb4,
        float* __restrict__ out,
        int n) {
    int i = blockIdx.x * blockDim.x + threadIdx.x;
    if (i >= n) return;
    float x, y, z; bool inside;
    load_p01(pts, i, x, y, z, inside);
    float c0 = 0.0f, c1 = 0.0f, c2 = 0.0f, sg = 0.0f;
    if (inside) {
        float4 acc = make_float4(0.0f, 0.0f, 0.0f, 0.0f);
        trilerp_acc<16>(cb0, x, y, z, acc);
        trilerp_acc<32>(cb1, x, y, z, acc);
        trilerp_acc<64>(cb2, x, y, z, acc);
        trilerp_acc<128>(cb3, x, y, z, acc);
        trilerp_acc<256>(cb4, x, y, z, acc);
        c0 = acc.x; c1 = acc.y; c2 = acc.z; sg = expf(acc.w);
    }
    out[3 * i + 0] = c0;
    out[3 * i + 1] = c1;
    out[3 * i + 2] = c2;
    out[(size_t)3 * n + i] = sg;
}

extern "C" void kernel_launch(void* const* d_in, const int* in_sizes, int n_in,
                              void* d_out, int out_size, void* d_ws, size_t ws_size,
                              hipStream_t stream) {
    const float* pts = (const float*)d_in[0];
    const float4* cb0 = (const float4*)d_in[2];
    const float4* cb1 = (const float4*)d_in[3];
    const float4* cb2 = (const float4*)d_in[4];
    const float4* cb3 = (const float4*)d_in[5];
    const float4* cb4 = (const float4*)d_in[6];
    float* out = (float*)d_out;

    int n = in_sizes[0] / 3;

    const int histTotal = kNBins * kNB;
    const int nChunks   = (histTotal + 1023) / 1024;

    size_t off_keys = 0;
    size_t off_spts = (off_keys + (size_t)n * 4 + 15) & ~(size_t)15;
    size_t off_hist = off_spts + (size_t)n * 16;
    size_t off_part = off_hist + (size_t)histTotal * 4;
    size_t need     = off_part + (size_t)nChunks * 4;

    dim3 block(256);
    int nwg = (n + 255) / 256;

    if (ws_size < need) {
        direct_kernel<<<dim3(nwg), block, 0, stream>>>(pts, cb0, cb1, cb2, cb3, cb4, out, n);
        return;
    }

    unsigned* keys      = (unsigned*)((char*)d_ws + off_keys);
    float4*   spts      = (float4*)((char*)d_ws + off_spts);
    unsigned* blockHist = (unsigned*)((char*)d_ws + off_hist);
    unsigned* partials  = (unsigned*)((char*)d_ws + off_part);

    int chunk = (n + kNB - 1) / kNB;

    keys_hist_kernel<<<dim3(kNB), block, 0, stream>>>(pts, keys, blockHist, n, chunk);
    scan_chunks_kernel<<<dim3(nChunks), block, 0, stream>>>(blockHist, partials, histTotal);
    scan_partials_kernel<<<dim3(1), block, 0, stream>>>(partials, nChunks);
    scan_add_kernel<<<dim3(nChunks), block, 0, stream>>>(blockHist, partials, histTotal);
    scatter_kernel<<<dim3(kNB), block, 0, stream>>>(pts, keys, blockHist, spts, out, n, chunk);
    compute_tiled_kernel<<<dim3(kG * kG * kG), dim3(512), 0, stream>>>(
        spts, blockHist, cb0, cb1, cb2, cb3, cb4, out, n);
}

// Round 6
// 317.849 us; speedup vs baseline: 1.1654x; 1.0089x over previous
//
#include <hip/hip_runtime.h>
#include <math.h>

static constexpr float kSceneScale = 4.0f;
static constexpr int   kG     = 16;                 // sort grid per axis (cb4-cell aligned)
static constexpr int   kNBins = kG * kG * kG + 1;   // 4097, +1 = "outside"
static constexpr int   kNB    = 256;                // histogram blocks
static constexpr int   kDirectThresh = 48;          // bins below this skip LDS staging
static constexpr int   kS4 = 17;                    // staged cb4 span (16 cells + 1 corner)

__device__ __forceinline__ void fma4(float4& acc, float w, const float4& c) {
    acc.x = fmaf(w, c.x, acc.x);
    acc.y = fmaf(w, c.y, acc.y);
    acc.z = fmaf(w, c.z, acc.z);
    acc.w = fmaf(w, c.w, acc.w);
}

__device__ __forceinline__ unsigned bf16r(float f) {
    unsigned u = __float_as_uint(f);
    return (u + 0x7FFFu + ((u >> 16) & 1u)) >> 16;   // RTNE; inputs finite
}
__device__ __forceinline__ unsigned pk2(float lo, float hi) {
    return bf16r(lo) | (bf16r(hi) << 16);
}
__device__ __forceinline__ float4 bfdec(uint2 w) {
    float4 r;
    r.x = __uint_as_float(w.x << 16);
    r.y = __uint_as_float(w.x & 0xFFFF0000u);
    r.z = __uint_as_float(w.y << 16);
    r.w = __uint_as_float(w.y & 0xFFFF0000u);
    return r;
}

template <int RES>
__device__ __forceinline__ void trilerp_acc(const float4* __restrict__ cb,
                                            float x, float y, float z,
                                            float4& acc) {
    const float s = (float)(RES - 1);
    float fx = x * s, fy = y * s, fz = z * s;
    int x0 = min((int)fx, RES - 2);
    int y0 = min((int)fy, RES - 2);
    int z0 = min((int)fz, RES - 2);
    float tx = fx - (float)x0;
    float ty = fy - (float)y0;
    float tz = fz - (float)z0;
    int base = (x0 * RES + y0) * RES + z0;
    float4 c000 = cb[base];
    float4 c001 = cb[base + 1];
    float4 c010 = cb[base + RES];
    float4 c011 = cb[base + RES + 1];
    float4 c100 = cb[base + RES * RES];
    float4 c101 = cb[base + RES * RES + 1];
    float4 c110 = cb[base + RES * RES + RES];
    float4 c111 = cb[base + RES * RES + RES + 1];
    float wx0 = 1.0f - tx, wx1 = tx;
    float wy0 = 1.0f - ty, wy1 = ty;
    float wz0 = 1.0f - tz, wz1 = tz;
    fma4(acc, wx0 * wy0 * wz0, c000);
    fma4(acc, wx0 * wy0 * wz1, c001);
    fma4(acc, wx0 * wy1 * wz0, c010);
    fma4(acc, wx0 * wy1 * wz1, c011);
    fma4(acc, wx1 * wy0 * wz0, c100);
    fma4(acc, wx1 * wy0 * wz1, c101);
    fma4(acc, wx1 * wy1 * wz0, c110);
    fma4(acc, wx1 * wy1 * wz1, c111);
}

__device__ __forceinline__ void load_p01(const float* __restrict__ pts, int i,
                                         float& x, float& y, float& z, bool& inside) {
    float px = pts[3 * i + 0] * (1.0f / kSceneScale);
    float py = pts[3 * i + 1] * (1.0f / kSceneScale);
    float pz = pts[3 * i + 2] * (1.0f / kSceneScale);
    inside = (fabsf(px) < 0.5f) && (fabsf(py) < 0.5f) && (fabsf(pz) < 0.5f);
    x = fminf(fmaxf(px + 0.5f, 0.0f), 1.0f);
    y = fminf(fmaxf(py + 0.5f, 0.0f), 1.0f);
    z = fminf(fmaxf(pz + 0.5f, 0.0f), 1.0f);
}

// bin = cb4 cell >> 4 per axis, so the staged span is exactly 17^3
__device__ __forceinline__ unsigned point_key(const float* __restrict__ pts, int i) {
    float x, y, z; bool inside;
    load_p01(pts, i, x, y, z, inside);
    if (!inside) return (unsigned)(kNBins - 1);
    int x0 = min((int)(x * 255.0f), 254) >> 4;
    int y0 = min((int)(y * 255.0f), 254) >> 4;
    int z0 = min((int)(z * 255.0f), 254) >> 4;
    return (unsigned)((x0 * kG + y0) * kG + z0);
}

// ---------- Pass A: per-block LDS histogram ----------
__global__ __launch_bounds__(256) void keys_hist_kernel(
        const float* __restrict__ pts, unsigned* __restrict__ keys,
        unsigned* __restrict__ blockHist, int n, int chunk) {
    __shared__ unsigned hist[kNBins];
    int tid = threadIdx.x;
    for (int j = tid; j < kNBins; j += 256) hist[j] = 0;
    __syncthreads();
    int beg = blockIdx.x * chunk;
    int end = min(n, beg + chunk);
    for (int i = beg + tid; i < end; i += 256) {
        unsigned key = point_key(pts, i);
        keys[i] = key;
        atomicAdd(&hist[key], 1u);
    }
    __syncthreads();
    for (int j = tid; j < kNBins; j += 256) blockHist[(size_t)j * kNB + blockIdx.x] = hist[j];
}

// ---------- Pass B1: scan 1024-element chunks ----------
__global__ __launch_bounds__(256) void scan_chunks_kernel(
        unsigned* __restrict__ data, unsigned* __restrict__ partials, int total) {
    __shared__ unsigned sums[256];
    int tid = threadIdx.x;
    int base = blockIdx.x * 1024 + tid * 4;
    uint4 v = make_uint4(0u, 0u, 0u, 0u);
    if (base + 3 < total) {
        v = *(const uint4*)(data + base);
    } else {
        unsigned* p = (unsigned*)&v;
        for (int k = 0; k < 4; ++k) if (base + k < total) p[k] = data[base + k];
    }
    unsigned s1 = v.x + v.y, s2 = s1 + v.z, s3 = s2 + v.w;
    sums[tid] = s3;
    __syncthreads();
    for (int off = 1; off < 256; off <<= 1) {
        unsigned t = (tid >= off) ? sums[tid - off] : 0u;
        __syncthreads();
        sums[tid] += t;
        __syncthreads();
    }
    unsigned excl = sums[tid] - s3;
    uint4 o;
    o.x = excl; o.y = excl + v.x; o.z = excl + s1; o.w = excl + s2;
    if (base + 3 < total) {
        *(uint4*)(data + base) = o;
    } else {
        unsigned* p = (unsigned*)&o;
        for (int k = 0; k < 4; ++k) if (base + k < total) data[base + k] = p[k];
    }
    if (tid == 255) partials[blockIdx.x] = sums[255];
}

// ---------- Pass B2: scan partials (1 block) ----------
__global__ __launch_bounds__(256) void scan_partials_kernel(unsigned* __restrict__ partials, int m) {
    __shared__ unsigned buf[256];
    __shared__ unsigned carry_s;
    int tid = threadIdx.x;
    if (tid == 0) carry_s = 0u;
    __syncthreads();
    for (int base = 0; base < m; base += 256) {
        unsigned v = (base + tid < m) ? partials[base + tid] : 0u;
        buf[tid] = v;
        __syncthreads();
        for (int off = 1; off < 256; off <<= 1) {
            unsigned t = (tid >= off) ? buf[tid - off] : 0u;
            __syncthreads();
            buf[tid] += t;
            __syncthreads();
        }
        unsigned incl = buf[tid];
        unsigned c = carry_s;
        if (base + tid < m) partials[base + tid] = c + incl - v;
        __syncthreads();
        if (tid == 255) carry_s = c + incl;
        __syncthreads();
    }
}

// ---------- Pass B3: add chunk offsets back ----------
__global__ __launch_bounds__(256) void scan_add_kernel(
        unsigned* __restrict__ data, const unsigned* __restrict__ partials, int total) {
    int tid = threadIdx.x;
    int base = blockIdx.x * 1024 + tid * 4;
    unsigned p = partials[blockIdx.x];
    if (base + 3 < total) {
        uint4 v = *(const uint4*)(data + base);
        v.x += p; v.y += p; v.z += p; v.w += p;
        *(uint4*)(data + base) = v;
    } else {
        for (int k = 0; k < 4; ++k) if (base + k < total) data[base + k] += p;
    }
}

// ---------- Pass C: scatter payloads; outside points write zeros here ----------
__global__ __launch_bounds__(256) void scatter_kernel(
        const float* __restrict__ pts,
        const unsigned* __restrict__ keys, const unsigned* __restrict__ blockHist,
        float4* __restrict__ spts, float* __restrict__ out, int n, int chunk) {
    __shared__ unsigned offs[kNBins];
    int tid = threadIdx.x;
    for (int j = tid; j < kNBins; j += 256) offs[j] = blockHist[(size_t)j * kNB + blockIdx.x];
    __syncthreads();
    int beg = blockIdx.x * chunk;
    int end = min(n, beg + chunk);
    for (int i = beg + tid; i < end; i += 256) {
        unsigned k = keys[i];
        float x, y, z; bool inside;
        load_p01(pts, i, x, y, z, inside);
        unsigned pos = atomicAdd(&offs[k], 1u);
        if (inside) {
            spts[pos] = make_float4(x, y, z, __uint_as_float((unsigned)i));
        } else {
            out[3 * i + 0] = 0.0f;
            out[3 * i + 1] = 0.0f;
            out[3 * i + 2] = 0.0f;
            out[(size_t)3 * n + i] = 0.0f;
        }
    }
}

// ---------- Pass D: one block per bin; stage ONLY cb4 (bf16) to LDS ----------
__global__ __launch_bounds__(512, 8) void compute_tiled_kernel(
        const float4* __restrict__ spts,
        const unsigned* __restrict__ blockHist,
        const float4* __restrict__ cb0,
        const float4* __restrict__ cb1,
        const float4* __restrict__ cb2,
        const float4* __restrict__ cb3,
        const float4* __restrict__ cb4,
        float* __restrict__ out,
        int n) {
    int bin = blockIdx.x;                    // 0..4095 (outside bin excluded)
    unsigned start = blockHist[(size_t)bin * kNB];
    unsigned end   = blockHist[(size_t)(bin + 1) * kNB];
    if (start >= end) return;

    int tid = threadIdx.x;

    if ((int)(end - start) < kDirectThresh) {
        // sparse bin: direct global gathers, skip staging
        for (unsigned t = start + tid; t < end; t += 512) {
            float4 s = spts[t];
            int i = (int)__float_as_uint(s.w);
            float4 acc = make_float4(0.0f, 0.0f, 0.0f, 0.0f);
            trilerp_acc<16>(cb0, s.x, s.y, s.z, acc);
            trilerp_acc<32>(cb1, s.x, s.y, s.z, acc);
            trilerp_acc<64>(cb2, s.x, s.y, s.z, acc);
            trilerp_acc<128>(cb3, s.x, s.y, s.z, acc);
            trilerp_acc<256>(cb4, s.x, s.y, s.z, acc);
            out[3 * i + 0] = acc.x;
            out[3 * i + 1] = acc.y;
            out[3 * i + 2] = acc.z;
            out[(size_t)3 * n + i] = expf(acc.w);
        }
        return;
    }

    __shared__ uint2 s4[kS4 * kS4 * kS4];    // 39304 B — 4 blocks/CU

    int bx = bin >> 8, by = (bin >> 4) & 15, bz = bin & 15;
    int ox = bx << 4, oy = by << 4, oz = bz << 4;

    for (int c = tid; c < kS4 * kS4 * kS4; c += 512) {
        int cz = c % kS4;
        int cy = (c / kS4) % kS4;
        int cx = c / (kS4 * kS4);
        int gx = min(ox + cx, 255);
        int gy = min(oy + cy, 255);
        int gz = min(oz + cz, 255);
        float4 v = cb4[((size_t)gx * 256 + gy) * 256 + gz];
        s4[c] = make_uint2(pk2(v.x, v.y), pk2(v.z, v.w));
    }
    __syncthreads();

    for (unsigned t = start + tid; t < end; t += 512) {
        float4 s = spts[t];
        int i = (int)__float_as_uint(s.w);
        float4 acc = make_float4(0.0f, 0.0f, 0.0f, 0.0f);
        trilerp_acc<16>(cb0, s.x, s.y, s.z, acc);
        trilerp_acc<32>(cb1, s.x, s.y, s.z, acc);
        trilerp_acc<64>(cb2, s.x, s.y, s.z, acc);
        trilerp_acc<128>(cb3, s.x, s.y, s.z, acc);

        // cb4 from LDS (bf16)
        {
            float fx = s.x * 255.0f, fy = s.y * 255.0f, fz = s.z * 255.0f;
            int x0 = min((int)fx, 254);
            int y0 = min((int)fy, 254);
            int z0 = min((int)fz, 254);
            float tx = fx - (float)x0;
            float ty = fy - (float)y0;
            float tz = fz - (float)z0;
            int base = ((x0 - ox) * kS4 + (y0 - oy)) * kS4 + (z0 - oz);
            uint2 w000 = s4[base];
            uint2 w001 = s4[base + 1];
            uint2 w010 = s4[base + kS4];
            uint2 w011 = s4[base + kS4 + 1];
            uint2 w100 = s4[base + kS4 * kS4];
            uint2 w101 = s4[base + kS4 * kS4 + 1];
            uint2 w110 = s4[base + kS4 * kS4 + kS4];
            uint2 w111 = s4[base + kS4 * kS4 + kS4 + 1];
            float wx0 = 1.0f - tx, wx1 = tx;
            float wy0 = 1.0f - ty, wy1 = ty;
            float wz0 = 1.0f - tz, wz1 = tz;
            fma4(acc, wx0 * wy0 * wz0, bfdec(w000));
            fma4(acc, wx0 * wy0 * wz1, bfdec(w001));
            fma4(acc, wx0 * wy1 * wz0, bfdec(w010));
            fma4(acc, wx0 * wy1 * wz1, bfdec(w011));
            fma4(acc, wx1 * wy0 * wz0, bfdec(w100));
            fma4(acc, wx1 * wy0 * wz1, bfdec(w101));
            fma4(acc, wx1 * wy1 * wz0, bfdec(w110));
            fma4(acc, wx1 * wy1 * wz1, bfdec(w111));
        }

        out[3 * i + 0] = acc.x;
        out[3 * i + 1] = acc.y;
        out[3 * i + 2] = acc.z;
        out[(size_t)3 * n + i] = expf(acc.w);
    }
}

// ---------- Fallback: direct kernel ----------
__global__ __launch_bounds__(256) void direct_kernel(
        const float* __restrict__ pts,
        const float4* __restrict__ cb0,
        const float4* __restrict__ cb1,
        const float4* __restrict__ cb2,
        const float4* __restrict__ cb3,
        const float4* __restrict__ cb4,
        float* __restrict__ out,
        int n) {
    int i = blockIdx.x * blockDim.x + threadIdx.x;
    if (i >= n) return;
    float x, y, z; bool inside;
    load_p01(pts, i, x, y, z, inside);
    float c0 = 0.0f, c1 = 0.0f, c2 = 0.0f, sg = 0.0f;
    if (inside) {
        float4 acc = make_float4(0.0f, 0.0f, 0.0f, 0.0f);
        trilerp_acc<16>(cb0, x, y, z, acc);
        trilerp_acc<32>(cb1, x, y, z, acc);
        trilerp_acc<64>(cb2, x, y, z, acc);
        trilerp_acc<128>(cb3, x, y, z, acc);
        trilerp_acc<256>(cb4, x, y, z, acc);
        c0 = acc.x; c1 = acc.y; c2 = acc.z; sg = expf(acc.w);
    }
    out[3 * i + 0] = c0;
    out[3 * i + 1] = c1;
    out[3 * i + 2] = c2;
    out[(size_t)3 * n + i] = sg;
}

extern "C" void kernel_launch(void* const* d_in, const int* in_sizes, int n_in,
                              void* d_out, int out_size, void* d_ws, size_t ws_size,
                              hipStream_t stream) {
    const float* pts = (const float*)d_in[0];
    const float4* cb0 = (const float4*)d_in[2];
    const float4* cb1 = (const float4*)d_in[3];
    const float4* cb2 = (const float4*)d_in[4];
    const float4* cb3 = (const float4*)d_in[5];
    const float4* cb4 = (const float4*)d_in[6];
    float* out = (float*)d_out;

    int n = in_sizes[0] / 3;

    const int histTotal = kNBins * kNB;
    const int nChunks   = (histTotal + 1023) / 1024;

    size_t off_keys = 0;
    size_t off_spts = (off_keys + (size_t)n * 4 + 15) & ~(size_t)15;
    size_t off_hist = off_spts + (size_t)n * 16;
    size_t off_part = off_hist + (size_t)histTotal * 4;
    size_t need     = off_part + (size_t)nChunks * 4;

    dim3 block(256);
    int nwg = (n + 255) / 256;

    if (ws_size < need) {
        direct_kernel<<<dim3(nwg), block, 0, stream>>>(pts, cb0, cb1, cb2, cb3, cb4, out, n);
        return;
    }

    unsigned* keys      = (unsigned*)((char*)d_ws + off_keys);
    float4*   spts      = (float4*)((char*)d_ws + off_spts);
    unsigned* blockHist = (unsigned*)((char*)d_ws + off_hist);
    unsigned* partials  = (unsigned*)((char*)d_ws + off_part);

    int chunk = (n + kNB - 1) / kNB;

    keys_hist_kernel<<<dim3(kNB), block, 0, stream>>>(pts, keys, blockHist, n, chunk);
    scan_chunks_kernel<<<dim3(nChunks), block, 0, stream>>>(blockHist, partials, histTotal);
    scan_partials_kernel<<<dim3(1), block, 0, stream>>>(partials, nChunks);
    scan_add_kernel<<<dim3(nChunks), block, 0, stream>>>(blockHist, partials, histTotal);
    scatter_kernel<<<dim3(kNB), block, 0, stream>>>(pts, keys, blockHist, spts, out, n, chunk);
    compute_tiled_kernel<<<dim3(kG * kG * kG), dim3(512), 0, stream>>>(
        spts, blockHist, cb0, cb1, cb2, cb3, cb4, out, n);
}

// Round 7
// 303.747 us; speedup vs baseline: 1.2195x; 1.0464x over previous
//
#include <hip/hip_runtime.h>
#include <math.h>

static constexpr float kSceneScale = 4.0f;
static constexpr int   kG     = 16;                 // sort grid per axis (cb4-cell aligned)
static constexpr int   kNBins = kG * kG * kG + 1;   // 4097, +1 = "outside"
static constexpr int   kNB    = 256;                // histogram blocks
static constexpr int   kDirectThresh = 48;          // items below this skip LDS staging
static constexpr int   kS4    = 17;                 // staged cb4 span (16 cells + 1 corner)
static constexpr int   kChunk = 512;                // points per work item

__device__ __forceinline__ void fma4(float4& acc, float w, const float4& c) {
    acc.x = fmaf(w, c.x, acc.x);
    acc.y = fmaf(w, c.y, acc.y);
    acc.z = fmaf(w, c.z, acc.z);
    acc.w = fmaf(w, c.w, acc.w);
}

__device__ __forceinline__ unsigned bf16r(float f) {
    unsigned u = __float_as_uint(f);
    return (u + 0x7FFFu + ((u >> 16) & 1u)) >> 16;   // RTNE; inputs finite
}
__device__ __forceinline__ unsigned pk2(float lo, float hi) {
    return bf16r(lo) | (bf16r(hi) << 16);
}
__device__ __forceinline__ float4 bfdec(uint2 w) {
    float4 r;
    r.x = __uint_as_float(w.x << 16);
    r.y = __uint_as_float(w.x & 0xFFFF0000u);
    r.z = __uint_as_float(w.y << 16);
    r.w = __uint_as_float(w.y & 0xFFFF0000u);
    return r;
}

template <int RES>
__device__ __forceinline__ void trilerp_acc(const float4* __restrict__ cb,
                                            float x, float y, float z,
                                            float4& acc) {
    const float s = (float)(RES - 1);
    float fx = x * s, fy = y * s, fz = z * s;
    int x0 = min((int)fx, RES - 2);
    int y0 = min((int)fy, RES - 2);
    int z0 = min((int)fz, RES - 2);
    float tx = fx - (float)x0;
    float ty = fy - (float)y0;
    float tz = fz - (float)z0;
    int base = (x0 * RES + y0) * RES + z0;
    float4 c000 = cb[base];
    float4 c001 = cb[base + 1];
    float4 c010 = cb[base + RES];
    float4 c011 = cb[base + RES + 1];
    float4 c100 = cb[base + RES * RES];
    float4 c101 = cb[base + RES * RES + 1];
    float4 c110 = cb[base + RES * RES + RES];
    float4 c111 = cb[base + RES * RES + RES + 1];
    float wx0 = 1.0f - tx, wx1 = tx;
    float wy0 = 1.0f - ty, wy1 = ty;
    float wz0 = 1.0f - tz, wz1 = tz;
    fma4(acc, wx0 * wy0 * wz0, c000);
    fma4(acc, wx0 * wy0 * wz1, c001);
    fma4(acc, wx0 * wy1 * wz0, c010);
    fma4(acc, wx0 * wy1 * wz1, c011);
    fma4(acc, wx1 * wy0 * wz0, c100);
    fma4(acc, wx1 * wy0 * wz1, c101);
    fma4(acc, wx1 * wy1 * wz0, c110);
    fma4(acc, wx1 * wy1 * wz1, c111);
}

__device__ __forceinline__ void load_p01(const float* __restrict__ pts, int i,
                                         float& x, float& y, float& z, bool& inside) {
    float px = pts[3 * i + 0] * (1.0f / kSceneScale);
    float py = pts[3 * i + 1] * (1.0f / kSceneScale);
    float pz = pts[3 * i + 2] * (1.0f / kSceneScale);
    inside = (fabsf(px) < 0.5f) && (fabsf(py) < 0.5f) && (fabsf(pz) < 0.5f);
    x = fminf(fmaxf(px + 0.5f, 0.0f), 1.0f);
    y = fminf(fmaxf(py + 0.5f, 0.0f), 1.0f);
    z = fminf(fmaxf(pz + 0.5f, 0.0f), 1.0f);
}

// bin = cb4 cell >> 4 per axis, so the staged span is exactly 17^3
__device__ __forceinline__ unsigned point_key(const float* __restrict__ pts, int i) {
    float x, y, z; bool inside;
    load_p01(pts, i, x, y, z, inside);
    if (!inside) return (unsigned)(kNBins - 1);
    int x0 = min((int)(x * 255.0f), 254) >> 4;
    int y0 = min((int)(y * 255.0f), 254) >> 4;
    int z0 = min((int)(z * 255.0f), 254) >> 4;
    return (unsigned)((x0 * kG + y0) * kG + z0);
}

// ---------- Pass A: per-block LDS histogram ----------
__global__ __launch_bounds__(256) void keys_hist_kernel(
        const float* __restrict__ pts, unsigned* __restrict__ keys,
        unsigned* __restrict__ blockHist, int n, int chunk) {
    __shared__ unsigned hist[kNBins];
    int tid = threadIdx.x;
    for (int j = tid; j < kNBins; j += 256) hist[j] = 0;
    __syncthreads();
    int beg = blockIdx.x * chunk;
    int end = min(n, beg + chunk);
    for (int i = beg + tid; i < end; i += 256) {
        unsigned key = point_key(pts, i);
        keys[i] = key;
        atomicAdd(&hist[key], 1u);
    }
    __syncthreads();
    for (int j = tid; j < kNBins; j += 256) blockHist[(size_t)j * kNB + blockIdx.x] = hist[j];
}

// ---------- Pass B1: scan 1024-element chunks ----------
__global__ __launch_bounds__(256) void scan_chunks_kernel(
        unsigned* __restrict__ data, unsigned* __restrict__ partials, int total) {
    __shared__ unsigned sums[256];
    int tid = threadIdx.x;
    int base = blockIdx.x * 1024 + tid * 4;
    uint4 v = make_uint4(0u, 0u, 0u, 0u);
    if (base + 3 < total) {
        v = *(const uint4*)(data + base);
    } else {
        unsigned* p = (unsigned*)&v;
        for (int k = 0; k < 4; ++k) if (base + k < total) p[k] = data[base + k];
    }
    unsigned s1 = v.x + v.y, s2 = s1 + v.z, s3 = s2 + v.w;
    sums[tid] = s3;
    __syncthreads();
    for (int off = 1; off < 256; off <<= 1) {
        unsigned t = (tid >= off) ? sums[tid - off] : 0u;
        __syncthreads();
        sums[tid] += t;
        __syncthreads();
    }
    unsigned excl = sums[tid] - s3;
    uint4 o;
    o.x = excl; o.y = excl + v.x; o.z = excl + s1; o.w = excl + s2;
    if (base + 3 < total) {
        *(uint4*)(data + base) = o;
    } else {
        unsigned* p = (unsigned*)&o;
        for (int k = 0; k < 4; ++k) if (base + k < total) data[base + k] = p[k];
    }
    if (tid == 255) partials[blockIdx.x] = sums[255];
}

// ---------- Pass B2: scan partials (1 block) ----------
__global__ __launch_bounds__(256) void scan_partials_kernel(unsigned* __restrict__ partials, int m) {
    __shared__ unsigned buf[256];
    __shared__ unsigned carry_s;
    int tid = threadIdx.x;
    if (tid == 0) carry_s = 0u;
    __syncthreads();
    for (int base = 0; base < m; base += 256) {
        unsigned v = (base + tid < m) ? partials[base + tid] : 0u;
        buf[tid] = v;
        __syncthreads();
        for (int off = 1; off < 256; off <<= 1) {
            unsigned t = (tid >= off) ? buf[tid - off] : 0u;
            __syncthreads();
            buf[tid] += t;
            __syncthreads();
        }
        unsigned incl = buf[tid];
        unsigned c = carry_s;
        if (base + tid < m) partials[base + tid] = c + incl - v;
        __syncthreads();
        if (tid == 255) carry_s = c + incl;
        __syncthreads();
    }
}

// ---------- Pass B3: add chunk offsets back ----------
__global__ __launch_bounds__(256) void scan_add_kernel(
        unsigned* __restrict__ data, const unsigned* __restrict__ partials, int total) {
    int tid = threadIdx.x;
    int base = blockIdx.x * 1024 + tid * 4;
    unsigned p = partials[blockIdx.x];
    if (base + 3 < total) {
        uint4 v = *(const uint4*)(data + base);
        v.x += p; v.y += p; v.z += p; v.w += p;
        *(uint4*)(data + base) = v;
    } else {
        for (int k = 0; k < 4; ++k) if (base + k < total) data[base + k] += p;
    }
}

// ---------- Pass C: scatter payloads; outside points write zeros here ----------
__global__ __launch_bounds__(256) void scatter_kernel(
        const float* __restrict__ pts,
        const unsigned* __restrict__ keys, const unsigned* __restrict__ blockHist,
        float4* __restrict__ spts, float* __restrict__ out, int n, int chunk) {
    __shared__ unsigned offs[kNBins];
    int tid = threadIdx.x;
    for (int j = tid; j < kNBins; j += 256) offs[j] = blockHist[(size_t)j * kNB + blockIdx.x];
    __syncthreads();
    int beg = blockIdx.x * chunk;
    int end = min(n, beg + chunk);
    for (int i = beg + tid; i < end; i += 256) {
        unsigned k = keys[i];
        float x, y, z; bool inside;
        load_p01(pts, i, x, y, z, inside);
        unsigned pos = atomicAdd(&offs[k], 1u);
        if (inside) {
            spts[pos] = make_float4(x, y, z, __uint_as_float((unsigned)i));
        } else {
            out[3 * i + 0] = 0.0f;
            out[3 * i + 1] = 0.0f;
            out[3 * i + 2] = 0.0f;
            out[(size_t)3 * n + i] = 0.0f;
        }
    }
}

// ---------- Pass W: build balanced work list (1 block) ----------
__global__ __launch_bounds__(512) void build_work_kernel(
        const unsigned* __restrict__ blockHist,
        uint2* __restrict__ items, unsigned* __restrict__ numItems) {
    __shared__ unsigned counter;
    if (threadIdx.x == 0) counter = 0u;
    __syncthreads();
    for (int bin = threadIdx.x; bin < kG * kG * kG; bin += 512) {
        unsigned s = blockHist[(size_t)bin * kNB];
        unsigned e = blockHist[(size_t)(bin + 1) * kNB];
        unsigned cnt = e - s;
        if (cnt == 0u) continue;
        unsigned k = (cnt + kChunk - 1) / kChunk;
        unsigned base = atomicAdd(&counter, k);
        for (unsigned j = 0; j < k; ++j)
            items[base + j] = make_uint2((unsigned)bin, s + j * kChunk);
    }
    __syncthreads();
    if (threadIdx.x == 0) numItems[0] = counter;
}

// ---------- Pass D: one block per work item (<=512 points); stage cb4 bf16 ----------
__global__ __launch_bounds__(512, 8) void compute_tiled_kernel(
        const float4* __restrict__ spts,
        const unsigned* __restrict__ blockHist,
        const uint2* __restrict__ items,
        const unsigned* __restrict__ numItems,
        const float4* __restrict__ cb0,
        const float4* __restrict__ cb1,
        const float4* __restrict__ cb2,
        const float4* __restrict__ cb3,
        const float4* __restrict__ cb4,
        float* __restrict__ out,
        int n) {
    if (blockIdx.x >= numItems[0]) return;
    uint2 it = items[blockIdx.x];
    int bin = (int)it.x;
    unsigned start = it.y;
    unsigned binEnd = blockHist[(size_t)(bin + 1) * kNB];
    unsigned end = min(binEnd, start + (unsigned)kChunk);

    int tid = threadIdx.x;

    if ((int)(end - start) < kDirectThresh) {
        // sparse item: direct global gathers, skip staging
        for (unsigned t = start + tid; t < end; t += 512) {
            float4 s = spts[t];
            int i = (int)__float_as_uint(s.w);
            float4 acc = make_float4(0.0f, 0.0f, 0.0f, 0.0f);
            trilerp_acc<16>(cb0, s.x, s.y, s.z, acc);
            trilerp_acc<32>(cb1, s.x, s.y, s.z, acc);
            trilerp_acc<64>(cb2, s.x, s.y, s.z, acc);
            trilerp_acc<128>(cb3, s.x, s.y, s.z, acc);
            trilerp_acc<256>(cb4, s.x, s.y, s.z, acc);
            out[3 * i + 0] = acc.x;
            out[3 * i + 1] = acc.y;
            out[3 * i + 2] = acc.z;
            out[(size_t)3 * n + i] = expf(acc.w);
        }
        return;
    }

    __shared__ uint2 s4[kS4 * kS4 * kS4];    // 39304 B — 4 blocks/CU

    int bx = bin >> 8, by = (bin >> 4) & 15, bz = bin & 15;
    int ox = bx << 4, oy = by << 4, oz = bz << 4;

    for (int c = tid; c < kS4 * kS4 * kS4; c += 512) {
        int cz = c % kS4;
        int cy = (c / kS4) % kS4;
        int cx = c / (kS4 * kS4);
        int gx = min(ox + cx, 255);
        int gy = min(oy + cy, 255);
        int gz = min(oz + cz, 255);
        float4 v = cb4[((size_t)gx * 256 + gy) * 256 + gz];
        s4[c] = make_uint2(pk2(v.x, v.y), pk2(v.z, v.w));
    }
    __syncthreads();

    unsigned t = start + tid;
    if (t < end) {
        float4 s = spts[t];
        int i = (int)__float_as_uint(s.w);
        float4 acc = make_float4(0.0f, 0.0f, 0.0f, 0.0f);
        trilerp_acc<16>(cb0, s.x, s.y, s.z, acc);
        trilerp_acc<32>(cb1, s.x, s.y, s.z, acc);
        trilerp_acc<64>(cb2, s.x, s.y, s.z, acc);
        trilerp_acc<128>(cb3, s.x, s.y, s.z, acc);

        // cb4 from LDS (bf16)
        {
            float fx = s.x * 255.0f, fy = s.y * 255.0f, fz = s.z * 255.0f;
            int x0 = min((int)fx, 254);
            int y0 = min((int)fy, 254);
            int z0 = min((int)fz, 254);
            float tx = fx - (float)x0;
            float ty = fy - (float)y0;
            float tz = fz - (float)z0;
            int base = ((x0 - ox) * kS4 + (y0 - oy)) * kS4 + (z0 - oz);
            uint2 w000 = s4[base];
            uint2 w001 = s4[base + 1];
            uint2 w010 = s4[base + kS4];
            uint2 w011 = s4[base + kS4 + 1];
            uint2 w100 = s4[base + kS4 * kS4];
            uint2 w101 = s4[base + kS4 * kS4 + 1];
            uint2 w110 = s4[base + kS4 * kS4 + kS4];
            uint2 w111 = s4[base + kS4 * kS4 + kS4 + 1];
            float wx0 = 1.0f - tx, wx1 = tx;
            float wy0 = 1.0f - ty, wy1 = ty;
            float wz0 = 1.0f - tz, wz1 = tz;
            fma4(acc, wx0 * wy0 * wz0, bfdec(w000));
            fma4(acc, wx0 * wy0 * wz1, bfdec(w001));
            fma4(acc, wx0 * wy1 * wz0, bfdec(w010));
            fma4(acc, wx0 * wy1 * wz1, bfdec(w011));
            fma4(acc, wx1 * wy0 * wz0, bfdec(w100));
            fma4(acc, wx1 * wy0 * wz1, bfdec(w101));
            fma4(acc, wx1 * wy1 * wz0, bfdec(w110));
            fma4(acc, wx1 * wy1 * wz1, bfdec(w111));
        }

        out[3 * i + 0] = acc.x;
        out[3 * i + 1] = acc.y;
        out[3 * i + 2] = acc.z;
        out[(size_t)3 * n + i] = expf(acc.w);
    }
}

// ---------- Fallback: direct kernel ----------
__global__ __launch_bounds__(256) void direct_kernel(
        const float* __restrict__ pts,
        const float4* __restrict__ cb0,
        const float4* __restrict__ cb1,
        const float4* __restrict__ cb2,
        const float4* __restrict__ cb3,
        const float4* __restrict__ cb4,
        float* __restrict__ out,
        int n) {
    int i = blockIdx.x * blockDim.x + threadIdx.x;
    if (i >= n) return;
    float x, y, z; bool inside;
    load_p01(pts, i, x, y, z, inside);
    float c0 = 0.0f, c1 = 0.0f, c2 = 0.0f, sg = 0.0f;
    if (inside) {
        float4 acc = make_float4(0.0f, 0.0f, 0.0f, 0.0f);
        trilerp_acc<16>(cb0, x, y, z, acc);
        trilerp_acc<32>(cb1, x, y, z, acc);
        trilerp_acc<64>(cb2, x, y, z, acc);
        trilerp_acc<128>(cb3, x, y, z, acc);
        trilerp_acc<256>(cb4, x, y, z, acc);
        c0 = acc.x; c1 = acc.y; c2 = acc.z; sg = expf(acc.w);
    }
    out[3 * i + 0] = c0;
    out[3 * i + 1] = c1;
    out[3 * i + 2] = c2;
    out[(size_t)3 * n + i] = sg;
}

extern "C" void kernel_launch(void* const* d_in, const int* in_sizes, int n_in,
                              void* d_out, int out_size, void* d_ws, size_t ws_size,
                              hipStream_t stream) {
    const float* pts = (const float*)d_in[0];
    const float4* cb0 = (const float4*)d_in[2];
    const float4* cb1 = (const float4*)d_in[3];
    const float4* cb2 = (const float4*)d_in[4];
    const float4* cb3 = (const float4*)d_in[5];
    const float4* cb4 = (const float4*)d_in[6];
    float* out = (float*)d_out;

    int n = in_sizes[0] / 3;

    const int histTotal = kNBins * kNB;
    const int nChunks   = (histTotal + 1023) / 1024;
    const int maxItems  = kG * kG * kG + (n + kChunk - 1) / kChunk;

    size_t off_keys  = 0;
    size_t off_spts  = (off_keys + (size_t)n * 4 + 15) & ~(size_t)15;
    size_t off_hist  = off_spts + (size_t)n * 16;
    size_t off_part  = off_hist + (size_t)histTotal * 4;
    size_t off_items = (off_part + (size_t)nChunks * 4 + 7) & ~(size_t)7;
    size_t off_nitem = off_items + (size_t)maxItems * 8;
    size_t need      = off_nitem + 4;

    dim3 block(256);
    int nwg = (n + 255) / 256;

    if (ws_size < need) {
        direct_kernel<<<dim3(nwg), block, 0, stream>>>(pts, cb0, cb1, cb2, cb3, cb4, out, n);
        return;
    }

    unsigned* keys      = (unsigned*)((char*)d_ws + off_keys);
    float4*   spts      = (float4*)((char*)d_ws + off_spts);
    unsigned* blockHist = (unsigned*)((char*)d_ws + off_hist);
    unsigned* partials  = (unsigned*)((char*)d_ws + off_part);
    uint2*    items     = (uint2*)((char*)d_ws + off_items);
    unsigned* numItems  = (unsigned*)((char*)d_ws + off_nitem);

    int chunk = (n + kNB - 1) / kNB;

    keys_hist_kernel<<<dim3(kNB), block, 0, stream>>>(pts, keys, blockHist, n, chunk);
    scan_chunks_kernel<<<dim3(nChunks), block, 0, stream>>>(blockHist, partials, histTotal);
    scan_partials_kernel<<<dim3(1), block, 0, stream>>>(partials, nChunks);
    scan_add_kernel<<<dim3(nChunks), block, 0, stream>>>(blockHist, partials, histTotal);
    scatter_kernel<<<dim3(kNB), block, 0, stream>>>(pts, keys, blockHist, spts, out, n, chunk);
    build_work_kernel<<<dim3(1), dim3(512), 0, stream>>>(blockHist, items, numItems);
    compute_tiled_kernel<<<dim3(maxItems), dim3(512), 0, stream>>>(
        spts, blockHist, items, numItems, cb0, cb1, cb2, cb3, cb4, out, n);
}